// Round 3
// baseline (84.485 us; speedup 1.0000x reference)
//
#include <hip/hip_runtime.h>
#include <math.h>

#define BB 4
#define NN 16384
#define CC 128
#define MM 128
#define SS 512
#define OUT_ROW 131   // 3 coords + 128 features
#define NSEG 256      // 16384 / 64 segments per box
#define G 8           // row-groups per box in gather kernel
#define RPG (SS / G)  // 64 rows per group

// ---------------- K1: per-box stable in-box index selection ----------------
__global__ __launch_bounds__(512) void k1_select(
    const float* __restrict__ points,   // (B, N, 3)
    const float* __restrict__ boxes,    // (B, M, 7)
    int* __restrict__ ws_idx,           // (B*M, SS)
    int* __restrict__ ws_cnt,           // (B*M)
    float* __restrict__ out_flag)       // (B*M) as float 0/1
{
    const int bm   = blockIdx.x;
    const int b    = bm >> 7;
    const int m    = bm & (MM - 1);
    const int tid  = threadIdx.x;
    const int lane = tid & 63;
    const int wave = tid >> 6;

    __shared__ unsigned long long s_mask[NSEG];
    __shared__ int s_wsum[4];

    // box params, enlarged: cz -= 0.5, d* += 1.0
    const float* bx = boxes + (size_t)(b * MM + m) * 7;
    const float cx  = bx[0];
    const float cy  = bx[1];
    const float cz  = __fadd_rn(bx[2], -0.5f);
    const float hx  = __fmul_rn(__fadd_rn(bx[3], 1.0f), 0.5f);
    const float hy  = __fmul_rn(__fadd_rn(bx[4], 1.0f), 0.5f);
    const float hz  = __fmul_rn(__fadd_rn(bx[5], 1.0f), 0.5f);
    const float yaw = bx[6];
    const float cosa = (float)cos((double)yaw);
    const float sina = (float)sin((double)yaw);
    const float zc   = __fadd_rn(cz, hz);

    const float* pbase = points + (size_t)b * NN * 3;

    // ---- Pass A: wave w handles segments [w*32, w*32+32) ----
    #pragma unroll 4
    for (int k = 0; k < 32; ++k) {
        const int s = wave * 32 + k;
        const int i = s * 64 + lane;
        const float px = pbase[i * 3 + 0];
        const float py = pbase[i * 3 + 1];
        const float pz = pbase[i * 3 + 2];
        const float sx = __fadd_rn(px, -cx);
        const float sy = __fadd_rn(py, -cy);
        const float lx = __fadd_rn(__fmul_rn(sx, cosa), __fmul_rn(sy, sina));
        const float ly = __fadd_rn(__fmul_rn(-sx, sina), __fmul_rn(sy, cosa));
        const bool in_box = (fabsf(lx) < hx) & (fabsf(ly) < hy) &
                            (fabsf(__fadd_rn(pz, -zc)) <= hz);
        const unsigned long long mask = __ballot(in_box);
        if (lane == 0) s_mask[s] = mask;
    }
    __syncthreads();

    // ---- Pass B: prefix scan over 256 segment counts (threads 0..255) ----
    unsigned long long mymask = 0ull;
    int c = 0;
    if (tid < NSEG) {
        mymask = s_mask[tid];
        c = __popcll(mymask);
    }
    int inc = c;
    #pragma unroll
    for (int d = 1; d < 64; d <<= 1) {
        int v = __shfl_up(inc, d);
        if (lane >= d) inc += v;
    }
    if (tid < NSEG && lane == 63) s_wsum[wave] = inc;
    __syncthreads();

    int woff = 0, total = 0;
    #pragma unroll
    for (int w = 0; w < 4; ++w) {
        const int v = s_wsum[w];
        if (w < wave) woff += v;
        total += v;
    }

    // ---- Pass C: emit indices (stable ascending order), first SS only ----
    if (tid < NSEG) {
        int base = woff + inc - c;          // exclusive prefix
        if (base < SS) {
            unsigned long long mk = mymask;
            int* dst = ws_idx + (size_t)bm * SS;
            while (mk) {
                const int bit = __ffsll(mk) - 1;
                mk &= mk - 1;
                dst[base] = tid * 64 + bit;
                if (++base >= SS) break;
            }
        }
    }
    if (tid == 0) {
        ws_cnt[bm] = total;
        out_flag[bm] = (total == 0) ? 1.0f : 0.0f;
    }
}

// ---------------- K2: gather + stream-write ----------------
// 4096 blocks (box x row-group) x 256 threads (4 waves).
// float4 gather loads (2 rows per wave-instruction), non-temporal stores
// so the 137 MB output stream doesn't evict the feature slice from L2.
__global__ __launch_bounds__(256) void k2_gather(
    const float* __restrict__ points,
    const float* __restrict__ feats,    // (B, N, C)
    const int* __restrict__ ws_idx,
    const int* __restrict__ ws_cnt,
    float* __restrict__ out_feat)       // (B, M, S, 131)
{
    const int blk = blockIdx.x;
    const int bm  = blk >> 3;
    const int g   = blk & (G - 1);
    const int row0 = g * RPG;
    const int tid  = threadIdx.x;

    const int cnt = ws_cnt[bm];
    float* obase = out_feat + (size_t)bm * SS * OUT_ROW;

    if (cnt == 0) {
        float* o = obase + (size_t)row0 * OUT_ROW;
        for (int e = tid; e < RPG * OUT_ROW; e += 256)
            __builtin_nontemporal_store(0.0f, o + e);
        return;
    }

    __shared__ int s_pi[RPG];
    if (tid < RPG) {
        const int row = row0 + tid;
        const int j = (row < cnt) ? row : (row % cnt);
        s_pi[tid] = ws_idx[(size_t)bm * SS + j];
    }
    __syncthreads();

    const int lane = tid & 63;
    const int wave = tid >> 6;
    const int half = lane >> 5;        // 0/1: which row of the pair
    const int sl   = lane & 31;        // float4 slot within the row
    const int b = bm >> 7;
    const float* pbase = points + (size_t)b * NN * 3;
    const float* fbase = feats + (size_t)b * NN * CC;

    // each wave: 8 iterations x 2 rows; lanes 0-31 -> row 2*pr, 32-63 -> 2*pr+1
    #pragma unroll 4
    for (int pr = wave; pr < RPG / 2; pr += 4) {
        const int r  = pr * 2 + half;
        const int pi = s_pi[r];
        const float4 v = *(const float4*)(fbase + (size_t)pi * CC + sl * 4);
        float* orow = obase + (size_t)(row0 + r) * OUT_ROW;
        float* od = orow + 3 + sl * 4;
        __builtin_nontemporal_store(v.x, od + 0);
        __builtin_nontemporal_store(v.y, od + 1);
        __builtin_nontemporal_store(v.z, od + 2);
        __builtin_nontemporal_store(v.w, od + 3);
        if (sl < 3)
            __builtin_nontemporal_store(pbase[pi * 3 + sl], orow + sl);
    }
}

extern "C" void kernel_launch(void* const* d_in, const int* in_sizes, int n_in,
                              void* d_out, int out_size, void* d_ws, size_t ws_size,
                              hipStream_t stream) {
    const float* points = (const float*)d_in[0];
    const float* feats  = (const float*)d_in[1];
    const float* boxes  = (const float*)d_in[2];
    float* out_feat = (float*)d_out;
    float* out_flag = (float*)d_out + (size_t)BB * MM * SS * OUT_ROW;

    int* ws_idx = (int*)d_ws;                       // 512*512 ints = 1 MB
    int* ws_cnt = ws_idx + (size_t)BB * MM * SS;    // 512 ints

    k1_select<<<BB * MM, 512, 0, stream>>>(points, boxes, ws_idx, ws_cnt, out_flag);
    k2_gather<<<BB * MM * G, 256, 0, stream>>>(points, feats, ws_idx, ws_cnt, out_feat);
}